// Round 4
// baseline (1963.640 us; speedup 1.0000x reference)
//
#include <hip/hip_runtime.h>
#include <hip/hip_cooperative_groups.h>

namespace cg = cooperative_groups;

// TreeLstmDecoder: B=64 trees, K=4, D=6, V=600, L=256, N_PER=1365, N=87360.
// Structure:
//  - ONE cooperative kernel runs the entire recurrence (pack, s=0 LSTMs, all
//    depth/sibling GEMM+LSTM phases) with grid.sync() between phases (28
//    syncs replace ~37 serial kernel launches). PP double-buffered so
//    S3(d) and hoist(d+1) share a phase.
//  - ONE fused tail kernel: 87360x602x256 GEMM + log-softmax, register-
//    resident (32 rows/block, acc[2][10] f32x4/thread), writes out directly.
//  - Fast transcendentals (__expf-based sigm/tanh, __logf) throughout: error
//    ~1e-6, invisible under bf16 rounding.
//  - Non-cooperative fallback path (same device functions, per-phase
//    launches) if cooperative launch is unavailable/fails.

typedef unsigned short u16;
typedef short bf16x8 __attribute__((ext_vector_type(8)));
typedef float f32x4 __attribute__((ext_vector_type(4)));

#define NPER 1365
#define VDIM 600
#define VD2  602

__device__ __forceinline__ float b2f(u16 h) {
  union { unsigned u; float f; } v; v.u = ((unsigned)h) << 16; return v.f;
}
__device__ __forceinline__ u16 f2bf(float f) {
  union { float f; unsigned u; } v; v.f = f;
  unsigned r = v.u + 0x7fff + ((v.u >> 16) & 1);
  return (u16)(r >> 16);
}
__device__ __forceinline__ float fsigm(float x) {
  return __fdividef(1.f, 1.f + __expf(-x));
}
__device__ __forceinline__ float ftanh(float x) {
  float e = __expf(-2.f * fabsf(x));
  float r = __fdividef(1.f - e, 1.f + e);
  return x < 0.f ? -r : r;
}

struct Args {
  const float *Upar, *Whhp, *Usib, *Whhs, *z, *Wihp, *Wihs, *Wlab, *Wd, *Ww,
              *blab, *bd, *bw, *bihp, *bhhp, *bihs, *bhhs;
  const int* feat;
  u16 *UPWHHP, *USWHHS, *ZBF, *WIHPT, *WIHST, *WEXT;
  float *BE, *BP, *BS;
  u16 *HP0, *HP1, *CP0, *CP1, *HS0, *HS1, *CS0, *CS1, *HS0A, *CS0A,
      *PP0, *PP1, *GATES, *GATESP, *HPRED;
};

// ---------------- device phases ---------------------------------------------

__device__ void dev_pack(const Args& a, int bid, int nb) {
  const int TOT = 2057306;
  for (int i0 = bid * 256 + (int)threadIdx.x; i0 < TOT; i0 += nb * 256) {
    int i = i0;
    if (i < 327680) {
      int r = i >> 8, c = i & 255;
      a.UPWHHP[i] = f2bf(r < 256 ? a.Upar[(r << 8) | c]
                                 : a.Whhp[((r - 256) << 8) | c]);
    } else if ((i -= 327680) < 327680) {
      int r = i >> 8, c = i & 255;
      a.USWHHS[i] = f2bf(r < 256 ? a.Usib[(r << 8) | c]
                                 : a.Whhs[((r - 256) << 8) | c]);
    } else if ((i -= 327680) < 16384) {
      a.ZBF[i] = f2bf(a.z[i]);
    } else if ((i -= 16384) < 614400) {   // W_ih_p [1024,600] -> [600,1024]
      int r = i >> 10, c = i & 1023;
      a.WIHPT[i] = f2bf(a.Wihp[c * VDIM + r]);
    } else if ((i -= 614400) < 614400) {
      int r = i >> 10, c = i & 1023;
      a.WIHST[i] = f2bf(a.Wihs[c * VDIM + r]);
    } else if ((i -= 614400) < VD2 * 256) {
      int r = i >> 8, c = i & 255;
      float v = (r < VDIM) ? a.Wlab[r * 256 + c]
                           : ((r == VDIM) ? a.Wd[c] : a.Ww[c]);
      a.WEXT[i] = f2bf(v);
    } else if ((i -= VD2 * 256) < VD2) {
      a.BE[i] = (i < VDIM) ? a.blab[i] : ((i == VDIM) ? a.bd[0] : a.bw[0]);
    } else if ((i -= VD2) < 1024) {
      a.BP[i] = a.bihp[i] + a.bhhp[i];
    } else {
      i -= 1024;
      a.BS[i] = a.bihs[i] + a.bhhs[i];
    }
  }
}

// fused dual GEMM tiles: C = A*B^T, B=[1280,256] concat.
// n0<256: v=acc(+PPadd); optional rawPP; tanh(v)->HPRED node rows.
// n0>=256: gates[row,col-256]=raw bf16.
__device__ void dev_dual(int bid, int nb,
    const u16* A, const u16* B, const u16* PPadd, u16* rawPP,
    u16* gates, u16* node_out, int M, int nx, int ny, int pcs, int sps) {
  static __shared__ __align__(16) u16 As[128 * 40];
  static __shared__ __align__(16) u16 Bs[128 * 40];
  const int tid = threadIdx.x;
  const int wave = tid >> 6, lane = tid & 63;
  const int quad = lane >> 4, lr = lane & 15;
  const int wm = (wave >> 1) * 64, wn = (wave & 1) * 64;
  const int srow = tid >> 2;
  const int sch = (tid & 3) << 3;

  for (int tile = bid; tile < nx * ny; tile += nb) {
    const int m0 = (tile % nx) * 128, n0 = (tile / nx) * 128;
    f32x4 acc[4][4] = {};
    for (int t = 0; t < 8; ++t) {
      const int kk = t * 32;
      bf16x8 a0 = *(const bf16x8*)(A + (size_t)(m0 + srow) * 256 + kk + sch);
      bf16x8 a1 = *(const bf16x8*)(A + (size_t)(m0 + srow + 64) * 256 + kk + sch);
      bf16x8 b0 = *(const bf16x8*)(B + (size_t)(n0 + srow) * 256 + kk + sch);
      bf16x8 b1 = *(const bf16x8*)(B + (size_t)(n0 + srow + 64) * 256 + kk + sch);
      __syncthreads();
      *(bf16x8*)&As[srow * 40 + sch] = a0;
      *(bf16x8*)&As[(srow + 64) * 40 + sch] = a1;
      *(bf16x8*)&Bs[srow * 40 + sch] = b0;
      *(bf16x8*)&Bs[(srow + 64) * 40 + sch] = b1;
      __syncthreads();
      bf16x8 af[4], bfr[4];
#pragma unroll
      for (int tm = 0; tm < 4; ++tm)
        af[tm] = *(const bf16x8*)&As[(wm + tm * 16 + lr) * 40 + quad * 8];
#pragma unroll
      for (int tn = 0; tn < 4; ++tn)
        bfr[tn] = *(const bf16x8*)&Bs[(wn + tn * 16 + lr) * 40 + quad * 8];
#pragma unroll
      for (int tm = 0; tm < 4; ++tm)
#pragma unroll
        for (int tn = 0; tn < 4; ++tn)
          acc[tm][tn] = __builtin_amdgcn_mfma_f32_16x16x32_bf16(
              af[tm], bfr[tn], acc[tm][tn], 0, 0, 0);
    }

    const bool isg = (n0 >= 256);
#pragma unroll
    for (int tn = 0; tn < 4; ++tn) {
      int col = n0 + wn + tn * 16 + lr;
#pragma unroll
      for (int tm = 0; tm < 4; ++tm) {
#pragma unroll
        for (int r = 0; r < 4; ++r) {
          int row = m0 + wm + tm * 16 + quad * 4 + r;
          if (row >= M) continue;
          float v = acc[tm][tn][r];
          if (isg) {
            gates[(size_t)row * 1024 + (col - 256)] = f2bf(v);
          } else {
            if (PPadd) v += b2f(PPadd[(size_t)row * 256 + col]);
            if (rawPP) rawPP[(size_t)row * 256 + col] = f2bf(v);
            int tt = row >> pcs, j = row & ((1 << pcs) - 1);
            node_out[(size_t)(tt * NPER + sps + 4 * j) * 256 + col] =
                f2bf(ftanh(v));
          }
        }
      }
    }
  }
}

// s=0 sibling LSTM for ALL depths (h_prev=c_prev=0, no gates).
__device__ void dev_s0(const Args& a, int bid, int nb) {
  const int u = threadIdx.x;
  for (int g = bid; g < 21824; g += nb) {
    int off, pcs, start;
    if (g < 64)        { off = 0;    pcs = 0; start = 1;   }
    else if (g < 320)  { off = 64;   pcs = 2; start = 5;   }
    else if (g < 1344) { off = 320;  pcs = 4; start = 21;  }
    else if (g < 5440) { off = 1344; pcs = 6; start = 85;  }
    else               { off = 5440; pcs = 8; start = 341; }
    int lg = g - off;
    int t = lg >> pcs, j = lg & ((1 << pcs) - 1);
    int idx = t * NPER + start + 4 * j;
    int lab = a.feat[idx];
    const u16* wr = a.WIHST + lab * 1024;
    float gi = b2f(wr[u])       + a.BS[u];
    float gg = b2f(wr[512 + u]) + a.BS[512 + u];
    float go = b2f(wr[768 + u]) + a.BS[768 + u];
    float cn = fsigm(gi) * ftanh(gg);
    float hn = fsigm(go) * ftanh(cn);
    a.HS0A[(size_t)g * 256 + u] = f2bf(hn);
    a.CS0A[(size_t)g * 256 + u] = f2bf(cn);
  }
}

__device__ void dev_lstm_par(int bid, int nb, const u16* gates, const u16* wihT,
    const float* bias, const u16* c_in, const int* feat,
    u16* h_out, u16* c_out, int lsbits, int start, int ng) {
  const int u = threadIdx.x;
  for (int g = bid; g < ng; g += nb) {
    int t = g >> lsbits, p = g & ((1 << lsbits) - 1);
    int pr = lsbits ? ((t << (lsbits - 2)) | (p >> 2)) : g;
    int idx = t * NPER + start + p;
    int lab = feat[idx];
    const u16* wr = wihT + lab * 1024;
    const u16* gr = gates + (size_t)pr * 1024;
    float gi = b2f(wr[u])       + bias[u]       + b2f(gr[u]);
    float gf = b2f(wr[256 + u]) + bias[256 + u] + b2f(gr[256 + u]);
    float gg = b2f(wr[512 + u]) + bias[512 + u] + b2f(gr[512 + u]);
    float go = b2f(wr[768 + u]) + bias[768 + u] + b2f(gr[768 + u]);
    float c = c_in ? b2f(c_in[(size_t)pr * 256 + u]) : 0.f;
    float cn = fsigm(gf) * c + fsigm(gi) * ftanh(gg);
    float hn = fsigm(go) * ftanh(cn);
    h_out[(size_t)g * 256 + u] = f2bf(hn);
    c_out[(size_t)g * 256 + u] = f2bf(cn);
  }
}

__device__ void dev_lstm_sib(int bid, int nb, const u16* gates, const u16* wihT,
    const float* bias, const u16* c_in, const int* feat,
    u16* h_out, u16* c_out, int pcs, int sps, int ng) {
  const int u = threadIdx.x;
  for (int g = bid; g < ng; g += nb) {
    int t = g >> pcs, j = g & ((1 << pcs) - 1);
    int idx = t * NPER + sps + 4 * j;
    int lab = feat[idx];
    const u16* wr = wihT + lab * 1024;
    const u16* gr = gates + (size_t)g * 1024;
    float gi = b2f(wr[u])       + bias[u]       + b2f(gr[u]);
    float gf = b2f(wr[256 + u]) + bias[256 + u] + b2f(gr[256 + u]);
    float gg = b2f(wr[512 + u]) + bias[512 + u] + b2f(gr[512 + u]);
    float go = b2f(wr[768 + u]) + bias[768 + u] + b2f(gr[768 + u]);
    float c = b2f(c_in[(size_t)g * 256 + u]);
    float cn = fsigm(gf) * c + fsigm(gi) * ftanh(gg);
    float hn = fsigm(go) * ftanh(cn);
    h_out[(size_t)g * 256 + u] = f2bf(hn);
    c_out[(size_t)g * 256 + u] = f2bf(cn);
  }
}

// ---------------- cooperative mega-kernel -----------------------------------

__global__ __launch_bounds__(256, 2) void k_coop(Args a) {
  cg::grid_group grid = cg::this_grid();
  const int bid = blockIdx.x, nb = gridDim.x;

  dev_pack(a, bid, nb);
  grid.sync();

  // d0 hoist: hpred=tanh(z@Up^T) -> HPRED roots; gates=z@Whhp^T. Then s0.
  dev_dual(bid, nb, a.ZBF, a.UPWHHP, nullptr, nullptr, a.GATESP, a.HPRED,
           64, 1, 10, 0, 0);
  dev_s0(a, bid, nb);
  grid.sync();

  dev_lstm_par(bid, nb, a.GATESP, a.WIHPT, a.BP, nullptr, a.feat,
               a.HP0, a.CP0, 0, 0, 64);
  grid.sync();

  // H1
  dev_dual(bid, nb, a.HP0, a.UPWHHP, nullptr, a.PP1, a.GATESP, a.HPRED,
           64, 1, 10, 0, 1);
  grid.sync();

  const int starts[6] = {0, 1, 5, 21, 85, 341};
  const int s0off[6]  = {0, 0, 64, 320, 1344, 5440};
  u16* HPs[2] = {a.HP0, a.HP1};
  u16* CPs[2] = {a.CP0, a.CP1};
  u16* PPs[2] = {a.PP0, a.PP1};

  for (int d = 1; d <= 5; ++d) {
    const int G = 64 << (2 * (d - 1));
    const int pcs = 2 * (d - 1);
    const int st = starts[d];
    const int nx = (G + 127) >> 7;
    u16* PPd = PPs[d & 1];
    const u16* hs1 = a.HS0A + (size_t)s0off[d] * 256;
    const u16* cs1 = a.CS0A + (size_t)s0off[d] * 256;

    // PhA: s=1 sibling dual + parent LSTM (independent)
    dev_dual(bid, nb, hs1, a.USWHHS, PPd, nullptr, a.GATES, a.HPRED,
             G, nx, 10, pcs, st + 1);
    if (d < 5)
      dev_lstm_par(bid, nb, a.GATESP, a.WIHPT, a.BP, CPs[(d - 1) & 1], a.feat,
                   HPs[d & 1], CPs[d & 1], 2 * d, st, 64 << (2 * d));
    grid.sync();
    // PhB: s=1 sibling LSTM
    dev_lstm_sib(bid, nb, a.GATES, a.WIHST, a.BS, cs1, a.feat,
                 a.HS1, a.CS1, pcs, st + 1, G);
    grid.sync();
    // PhC: s=2 sibling dual
    dev_dual(bid, nb, a.HS1, a.USWHHS, PPd, nullptr, a.GATES, a.HPRED,
             G, nx, 10, pcs, st + 2);
    grid.sync();
    // PhD: s=2 sibling LSTM
    dev_lstm_sib(bid, nb, a.GATES, a.WIHST, a.BS, a.CS1, a.feat,
                 a.HS0, a.CS0, pcs, st + 2, G);
    grid.sync();
    // PhE: s=3 dual (hpred only) + next depth hoist
    dev_dual(bid, nb, a.HS0, a.USWHHS, PPd, nullptr, nullptr, a.HPRED,
             G, nx, 2, pcs, st + 3);
    if (d < 5) {
      const int M2 = 64 << (2 * d);
      const int nx2 = (M2 + 127) >> 7;
      const int ny2 = (d + 1 < 5) ? 10 : 2;
      dev_dual(bid, nb, HPs[d & 1], a.UPWHHP, nullptr, PPs[(d + 1) & 1],
               (d + 1 < 5) ? a.GATESP : nullptr, a.HPRED,
               M2, nx2, ny2, 2 * d, starts[d + 1]);
      grid.sync();
    }
  }
}

// ---------------- fallback wrappers (non-cooperative path) ------------------

__global__ __launch_bounds__(256) void k_w_pack(Args a) {
  dev_pack(a, blockIdx.x, gridDim.x);
}
__global__ __launch_bounds__(256) void k_w_s0(Args a) {
  dev_s0(a, blockIdx.x, gridDim.x);
}
__global__ __launch_bounds__(256) void k_w_dual(
    const u16* A, const u16* B, const u16* PPadd, u16* rawPP,
    u16* gates, u16* node_out, int M, int nx, int ny, int pcs, int sps) {
  dev_dual(blockIdx.x, gridDim.x, A, B, PPadd, rawPP, gates, node_out,
           M, nx, ny, pcs, sps);
}
__global__ __launch_bounds__(256) void k_w_par(
    const u16* gates, const u16* wihT, const float* bias, const u16* c_in,
    const int* feat, u16* h, u16* c, int lsbits, int start, int ng) {
  dev_lstm_par(blockIdx.x, gridDim.x, gates, wihT, bias, c_in, feat, h, c,
               lsbits, start, ng);
}
__global__ __launch_bounds__(256) void k_w_sib(
    const u16* gates, const u16* wihT, const float* bias, const u16* c_in,
    const int* feat, u16* h, u16* c, int pcs, int sps, int ng) {
  dev_lstm_sib(blockIdx.x, gridDim.x, gates, wihT, bias, c_in, feat, h, c,
               pcs, sps, ng);
}

// ---------------- fused tail: logits GEMM + log-softmax ---------------------
// 32 rows/block; wave w owns cols [w*160, w*160+160) as 10 tiles of 16;
// acc[2][10] f32x4/thread. A tile in LDS; B frags from L2. Exact max/expsum.
__global__ __launch_bounds__(256, 2) void k_mm_tail(
    const u16* __restrict__ A, const u16* __restrict__ B,
    const float* __restrict__ bias, float* __restrict__ out) {
  __shared__ __align__(16) u16 As[32 * 264];
  __shared__ float smax[32][4], ssum[32][4], slz[32];
  const int m0 = blockIdx.x * 32;
  const int tid = threadIdx.x;
  const int wave = tid >> 6, lane = tid & 63;
  const int quad = lane >> 4, lr = lane & 15;
  const int c0 = wave * 160;

#pragma unroll
  for (int c = 0; c < 4; ++c) {
    int idx = c * 256 + tid;
    int row = idx >> 5, ch = (idx & 31) << 3;
    *(bf16x8*)&As[row * 264 + ch] =
        *(const bf16x8*)(A + (size_t)(m0 + row) * 256 + ch);
  }
  __syncthreads();

  f32x4 acc[2][10] = {};
#pragma unroll
  for (int t = 0; t < 8; ++t) {
    bf16x8 af[2], bfr[10];
#pragma unroll
    for (int tm = 0; tm < 2; ++tm)
      af[tm] = *(const bf16x8*)&As[(tm * 16 + lr) * 264 + t * 32 + quad * 8];
#pragma unroll
    for (int tn = 0; tn < 10; ++tn)
      bfr[tn] = *(const bf16x8*)(B + (size_t)(c0 + tn * 16 + lr) * 256 +
                                 t * 32 + quad * 8);
#pragma unroll
    for (int tm = 0; tm < 2; ++tm)
#pragma unroll
      for (int tn = 0; tn < 10; ++tn)
        acc[tm][tn] = __builtin_amdgcn_mfma_f32_16x16x32_bf16(
            af[tm], bfr[tn], acc[tm][tn], 0, 0, 0);
  }

  float bv[10]; bool val[10];
#pragma unroll
  for (int tn = 0; tn < 10; ++tn) {
    int col = c0 + tn * 16 + lr;
    val[tn] = (col < VDIM);
    bv[tn] = (col < VD2) ? bias[col] : 0.f;
  }

#pragma unroll
  for (int tm = 0; tm < 2; ++tm) {
#pragma unroll
    for (int r = 0; r < 4; ++r) {
      float mx = -1e30f;
#pragma unroll
      for (int tn = 0; tn < 10; ++tn)
        if (val[tn]) mx = fmaxf(mx, acc[tm][tn][r] + bv[tn]);
#pragma unroll
      for (int o = 1; o < 16; o <<= 1) mx = fmaxf(mx, __shfl_xor(mx, o, 64));
      if (lr == 0) smax[tm * 16 + quad * 4 + r][wave] = mx;
    }
  }
  __syncthreads();
#pragma unroll
  for (int tm = 0; tm < 2; ++tm) {
#pragma unroll
    for (int r = 0; r < 4; ++r) {
      int row = tm * 16 + quad * 4 + r;
      float fm = fmaxf(fmaxf(smax[row][0], smax[row][1]),
                       fmaxf(smax[row][2], smax[row][3]));
      float se = 0.f;
#pragma unroll
      for (int tn = 0; tn < 10; ++tn)
        if (val[tn]) se += __expf(acc[tm][tn][r] + bv[tn] - fm);
#pragma unroll
      for (int o = 1; o < 16; o <<= 1) se += __shfl_xor(se, o, 64);
      if (lr == 0) ssum[row][wave] = se;
    }
  }
  __syncthreads();
  if (tid < 32) {
    float fm = fmaxf(fmaxf(smax[tid][0], smax[tid][1]),
                     fmaxf(smax[tid][2], smax[tid][3]));
    slz[tid] = fm + __logf(ssum[tid][0] + ssum[tid][1] +
                           ssum[tid][2] + ssum[tid][3]);
  }
  __syncthreads();

#pragma unroll
  for (int tm = 0; tm < 2; ++tm) {
#pragma unroll
    for (int tn = 0; tn < 10; ++tn) {
      int col = c0 + tn * 16 + lr;
      if (col >= VD2) continue;
#pragma unroll
      for (int r = 0; r < 4; ++r) {
        int row = tm * 16 + quad * 4 + r;
        float v = acc[tm][tn][r] + bv[tn];
        out[(size_t)(m0 + row) * VD2 + col] =
            (col < VDIM) ? (v - slz[row]) : fsigm(v);
      }
    }
  }
}

// ---------------- host ------------------------------------------------------

extern "C" void kernel_launch(void* const* d_in, const int* in_sizes, int n_in,
                              void* d_out, int out_size, void* d_ws, size_t ws_size,
                              hipStream_t stream) {
  char* w = (char*)d_ws;
  auto alloc = [&](size_t bytes) {
    char* p = w; w += (bytes + 255) & ~(size_t)255; return p;
  };

  Args a;
  a.z    = (const float*)d_in[0];
  a.feat = (const int*)d_in[1];
  a.Wihp = (const float*)d_in[2];
  a.Whhp = (const float*)d_in[3];
  a.bihp = (const float*)d_in[4];
  a.bhhp = (const float*)d_in[5];
  a.Wihs = (const float*)d_in[6];
  a.Whhs = (const float*)d_in[7];
  a.bihs = (const float*)d_in[8];
  a.bhhs = (const float*)d_in[9];
  a.Upar = (const float*)d_in[10];
  a.Usib = (const float*)d_in[11];
  a.Wlab = (const float*)d_in[12];
  a.blab = (const float*)d_in[13];
  a.Wd   = (const float*)d_in[14];
  a.bd   = (const float*)d_in[15];
  a.Ww   = (const float*)d_in[16];
  a.bw   = (const float*)d_in[17];
  float* out = (float*)d_out;

  a.UPWHHP = (u16*)alloc((size_t)1280 * 256 * 2);
  a.USWHHS = (u16*)alloc((size_t)1280 * 256 * 2);
  a.ZBF    = (u16*)alloc((size_t)128 * 256 * 2);    // rows 64..127: pad
  a.WIHPT  = (u16*)alloc((size_t)VDIM * 1024 * 2);
  a.WIHST  = (u16*)alloc((size_t)VDIM * 1024 * 2);
  a.WEXT   = (u16*)alloc((size_t)640 * 256 * 2);    // rows 602..639: pad
  a.BE     = (float*)alloc(VD2 * 4);
  a.BP     = (float*)alloc(1024 * 4);
  a.BS     = (float*)alloc(1024 * 4);
  const size_t SB = (size_t)16384 * 256 * 2;
  a.HP0 = (u16*)alloc(SB); a.HP1 = (u16*)alloc(SB);
  a.CP0 = (u16*)alloc(SB); a.CP1 = (u16*)alloc(SB);
  a.HS0 = (u16*)alloc(SB); a.HS1 = (u16*)alloc(SB);
  a.CS0 = (u16*)alloc(SB); a.CS1 = (u16*)alloc(SB);
  a.HS0A = (u16*)alloc((size_t)21824 * 256 * 2);
  a.CS0A = (u16*)alloc((size_t)21824 * 256 * 2);
  a.PP0 = (u16*)alloc(SB); a.PP1 = (u16*)alloc(SB);
  a.GATES  = (u16*)alloc((size_t)16384 * 1024 * 2);
  a.GATESP = (u16*)alloc((size_t)4096 * 1024 * 2);
  a.HPRED  = (u16*)alloc((size_t)87424 * 256 * 2);  // node-ordered, +pad

  // ---- cooperative path: one kernel for the whole recurrence
  int useCoop = 0;
  {
    int dev = 0;
    (void)hipGetDevice(&dev);
    int attr = 0;
    if (hipDeviceGetAttribute(&attr, hipDeviceAttributeCooperativeLaunch, dev)
            == hipSuccess && attr)
      useCoop = 1;
  }
  if (useCoop) {
    int occ = 0;
    if (hipOccupancyMaxActiveBlocksPerMultiprocessor(&occ, k_coop, 256, 0)
            != hipSuccess || occ < 1)
      occ = 1;
    int perCU = occ < 2 ? occ : 2;
    int nblk = 256 * perCU;
    void* cargs[] = {(void*)&a};
    if (hipLaunchCooperativeKernel(k_coop, dim3(nblk), dim3(256), cargs,
                                   (unsigned)0, stream) != hipSuccess)
      useCoop = 0;
  }

  if (!useCoop) {
    // ---- fallback: same phases as separate launches
    const int starts[6] = {0, 1, 5, 21, 85, 341};
    const int s0off[6]  = {0, 0, 64, 320, 1344, 5440};
    u16* HPs[2] = {a.HP0, a.HP1};
    u16* CPs[2] = {a.CP0, a.CP1};
    u16* PPs[2] = {a.PP0, a.PP1};

    k_w_pack<<<8038, 256, 0, stream>>>(a);
    k_w_dual<<<10, 256, 0, stream>>>(a.ZBF, a.UPWHHP, nullptr, nullptr,
                                     a.GATESP, a.HPRED, 64, 1, 10, 0, 0);
    k_w_s0<<<21824, 256, 0, stream>>>(a);
    k_w_par<<<64, 256, 0, stream>>>(a.GATESP, a.WIHPT, a.BP, nullptr, a.feat,
                                    a.HP0, a.CP0, 0, 0, 64);
    k_w_dual<<<10, 256, 0, stream>>>(a.HP0, a.UPWHHP, nullptr, a.PP1,
                                     a.GATESP, a.HPRED, 64, 1, 10, 0, 1);
    for (int d = 1; d <= 5; ++d) {
      const int G = 64 << (2 * (d - 1));
      const int pcs = 2 * (d - 1);
      const int st = starts[d];
      const int nx = (G + 127) >> 7;
      u16* PPd = PPs[d & 1];
      const u16* hs1 = a.HS0A + (size_t)s0off[d] * 256;
      const u16* cs1 = a.CS0A + (size_t)s0off[d] * 256;

      k_w_dual<<<nx * 10, 256, 0, stream>>>(hs1, a.USWHHS, PPd, nullptr,
                                            a.GATES, a.HPRED, G, nx, 10, pcs, st + 1);
      if (d < 5)
        k_w_par<<<64 << (2 * d), 256, 0, stream>>>(
            a.GATESP, a.WIHPT, a.BP, CPs[(d - 1) & 1], a.feat,
            HPs[d & 1], CPs[d & 1], 2 * d, st, 64 << (2 * d));
      k_w_sib<<<G, 256, 0, stream>>>(a.GATES, a.WIHST, a.BS, cs1, a.feat,
                                     a.HS1, a.CS1, pcs, st + 1, G);
      k_w_dual<<<nx * 10, 256, 0, stream>>>(a.HS1, a.USWHHS, PPd, nullptr,
                                            a.GATES, a.HPRED, G, nx, 10, pcs, st + 2);
      k_w_sib<<<G, 256, 0, stream>>>(a.GATES, a.WIHST, a.BS, a.CS1, a.feat,
                                     a.HS0, a.CS0, pcs, st + 2, G);
      k_w_dual<<<nx * 2, 256, 0, stream>>>(a.HS0, a.USWHHS, PPd, nullptr,
                                           nullptr, a.HPRED, G, nx, 2, pcs, st + 3);
      if (d < 5) {
        const int M2 = 64 << (2 * d);
        const int nx2 = (M2 + 127) >> 7;
        const int ny2 = (d + 1 < 5) ? 10 : 2;
        k_w_dual<<<nx2 * ny2, 256, 0, stream>>>(
            HPs[d & 1], a.UPWHHP, nullptr, PPs[(d + 1) & 1],
            (d + 1 < 5) ? a.GATESP : nullptr, a.HPRED,
            M2, nx2, ny2, 2 * d, starts[d + 1]);
      }
    }
  }

  // ---- fused tail: one kernel, GEMM + log-softmax -> out
  k_mm_tail<<<2730, 256, 0, stream>>>(a.HPRED, a.WEXT, a.BE, out);

  (void)in_sizes; (void)n_in; (void)out_size; (void)ws_size;
}

// Round 5
// 650.943 us; speedup vs baseline: 3.0166x; 3.0166x over previous
//
#include <hip/hip_runtime.h>

// TreeLstmDecoder: B=64 trees, K=4, D=6, V=600, L=256, N_PER=1365, N=87360.
// 20-launch schedule:
//  - k_pack: all weight conversions (1)
//  - k_lstm_s0: sibling state s=0 for ALL depths (1)   [labels only]
//  - Sibling chain BATCHED ACROSS DEPTHS (independent of parent chain):
//    3x k_dual (state_{k-1}@[Us;Whhs] -> UPROJ_k fp32 + gates) +
//    2x k_lstm_sibA (-> state_k), 21824 rows each        (5)
//  - Parent chain (depth-serial): 6x k_dual (P_d@[Up;Whhp] -> PPA + gatesP;
//    z-dual also writes root hpred) + 5x k_lstm_par      (11)
//  - k_assemble: hpred = tanh(PP_d[r] + UPROJ_s[r]) for all nodes (1)
//  - k_mm_tail: 87360x602x256 GEMM + log-softmax, register-resident (1)
// All GEMMs: C = A*B^T, K=256, bf16 operands, fp32 accumulate via MFMA.
// Fast transcendentals throughout (validated: absmax unchanged).

typedef unsigned short u16;
typedef short bf16x8 __attribute__((ext_vector_type(8)));
typedef float f32x4 __attribute__((ext_vector_type(4)));

#define NPER 1365
#define VDIM 600
#define VD2  602

__device__ __forceinline__ float b2f(u16 h) {
  union { unsigned u; float f; } v; v.u = ((unsigned)h) << 16; return v.f;
}
__device__ __forceinline__ u16 f2bf(float f) {
  union { float f; unsigned u; } v; v.f = f;
  unsigned r = v.u + 0x7fff + ((v.u >> 16) & 1);
  return (u16)(r >> 16);
}
__device__ __forceinline__ float fsigm(float x) {
  return __fdividef(1.f, 1.f + __expf(-x));
}
__device__ __forceinline__ float ftanh(float x) {
  float e = __expf(-2.f * fabsf(x));
  float r = __fdividef(1.f - e, 1.f + e);
  return x < 0.f ? -r : r;
}

// chain-row ladder: r -> (off, pcs, start) for depths 1..5
__device__ __forceinline__ void ladder(int r, int& off, int& pcs, int& start) {
  if (r < 64)        { off = 0;    pcs = 0; start = 1;   }
  else if (r < 320)  { off = 64;   pcs = 2; start = 5;   }
  else if (r < 1344) { off = 320;  pcs = 4; start = 21;  }
  else if (r < 5440) { off = 1344; pcs = 6; start = 85;  }
  else               { off = 5440; pcs = 8; start = 341; }
}

// ---------------- pack kernel -----------------------------------------------
__global__ void k_pack(
    const float* __restrict__ Upar, const float* __restrict__ Whhp,
    const float* __restrict__ Usib, const float* __restrict__ Whhs,
    const float* __restrict__ z, const float* __restrict__ Wihp,
    const float* __restrict__ Wihs, const float* __restrict__ Wlab,
    const float* __restrict__ Wd, const float* __restrict__ Ww,
    const float* __restrict__ blab, const float* __restrict__ bd,
    const float* __restrict__ bw, const float* __restrict__ bihp,
    const float* __restrict__ bhhp, const float* __restrict__ bihs,
    const float* __restrict__ bhhs,
    u16* __restrict__ UPWHHP, u16* __restrict__ USWHHS, u16* __restrict__ ZBF,
    u16* __restrict__ WIHPT, u16* __restrict__ WIHST, u16* __restrict__ WEXT,
    float* __restrict__ BE, float* __restrict__ BP, float* __restrict__ BS) {
  int i = blockIdx.x * 256 + threadIdx.x;
  if (i < 327680) {
    int r = i >> 8, c = i & 255;
    UPWHHP[i] = f2bf(r < 256 ? Upar[(r << 8) | c] : Whhp[((r - 256) << 8) | c]);
    return;
  }
  i -= 327680;
  if (i < 327680) {
    int r = i >> 8, c = i & 255;
    USWHHS[i] = f2bf(r < 256 ? Usib[(r << 8) | c] : Whhs[((r - 256) << 8) | c]);
    return;
  }
  i -= 327680;
  if (i < 16384) { ZBF[i] = f2bf(z[i]); return; }
  i -= 16384;
  if (i < 614400) {  // W_ih_p [1024,600] -> [600,1024]; coalesced writes
    int r = i >> 10, c = i & 1023;
    WIHPT[i] = f2bf(Wihp[c * VDIM + r]); return;
  }
  i -= 614400;
  if (i < 614400) {
    int r = i >> 10, c = i & 1023;
    WIHST[i] = f2bf(Wihs[c * VDIM + r]); return;
  }
  i -= 614400;
  if (i < VD2 * 256) {
    int r = i >> 8, c = i & 255;
    float v = (r < VDIM) ? Wlab[r * 256 + c] : ((r == VDIM) ? Wd[c] : Ww[c]);
    WEXT[i] = f2bf(v); return;
  }
  i -= VD2 * 256;
  if (i < VD2) { BE[i] = (i < VDIM) ? blab[i] : ((i == VDIM) ? bd[0] : bw[0]); return; }
  i -= VD2;
  if (i < 1024) { BP[i] = bihp[i] + bhhp[i]; return; }
  i -= 1024;
  if (i < 1024) { BS[i] = bihs[i] + bhhs[i]; return; }
}

// ---------------- dual GEMM: C = A*B^T, B=[1280,256] concat ------------------
// n0<256 tiles (the U-product), exactly one of:
//   hroot  : write f2bf(ftanh(acc)) to HPRED root rows (row=t -> idx t*NPER)
//   uproj  : write acc (fp32 raw) to uproj[row*256+col]
//   ppdst  : write f2bf(acc) to ppdst[(ppoff+row)*256+col]
// n0>=256 tiles: gates[row*1024 + (col-256)] = f2bf(acc).
__global__ __launch_bounds__(256) void k_dual(
    const u16* __restrict__ A, const u16* __restrict__ B,
    u16* __restrict__ ppdst, int ppoff, float* __restrict__ uproj,
    u16* __restrict__ hroot, u16* __restrict__ gates, int M) {
  __shared__ __align__(16) u16 As[128 * 40];
  __shared__ __align__(16) u16 Bs[128 * 40];
  const int m0 = blockIdx.x * 128, n0 = blockIdx.y * 128;
  const int tid = threadIdx.x;
  const int wave = tid >> 6, lane = tid & 63;
  const int quad = lane >> 4, lr = lane & 15;
  const int wm = (wave >> 1) * 64, wn = (wave & 1) * 64;
  const int srow = tid >> 2;
  const int sch = (tid & 3) << 3;

  f32x4 acc[4][4] = {};
  for (int t = 0; t < 8; ++t) {
    const int kk = t * 32;
    bf16x8 a0 = *(const bf16x8*)(A + (size_t)(m0 + srow) * 256 + kk + sch);
    bf16x8 a1 = *(const bf16x8*)(A + (size_t)(m0 + srow + 64) * 256 + kk + sch);
    bf16x8 b0 = *(const bf16x8*)(B + (size_t)(n0 + srow) * 256 + kk + sch);
    bf16x8 b1 = *(const bf16x8*)(B + (size_t)(n0 + srow + 64) * 256 + kk + sch);
    __syncthreads();
    *(bf16x8*)&As[srow * 40 + sch] = a0;
    *(bf16x8*)&As[(srow + 64) * 40 + sch] = a1;
    *(bf16x8*)&Bs[srow * 40 + sch] = b0;
    *(bf16x8*)&Bs[(srow + 64) * 40 + sch] = b1;
    __syncthreads();
    bf16x8 af[4], bfr[4];
#pragma unroll
    for (int tm = 0; tm < 4; ++tm)
      af[tm] = *(const bf16x8*)&As[(wm + tm * 16 + lr) * 40 + quad * 8];
#pragma unroll
    for (int tn = 0; tn < 4; ++tn)
      bfr[tn] = *(const bf16x8*)&Bs[(wn + tn * 16 + lr) * 40 + quad * 8];
#pragma unroll
    for (int tm = 0; tm < 4; ++tm)
#pragma unroll
      for (int tn = 0; tn < 4; ++tn)
        acc[tm][tn] = __builtin_amdgcn_mfma_f32_16x16x32_bf16(
            af[tm], bfr[tn], acc[tm][tn], 0, 0, 0);
  }

  const bool isg = (n0 >= 256);
#pragma unroll
  for (int tn = 0; tn < 4; ++tn) {
    int col = n0 + wn + tn * 16 + lr;
#pragma unroll
    for (int tm = 0; tm < 4; ++tm) {
#pragma unroll
      for (int r = 0; r < 4; ++r) {
        int row = m0 + wm + tm * 16 + quad * 4 + r;
        if (row >= M) continue;
        float v = acc[tm][tn][r];
        if (isg) {
          gates[(size_t)row * 1024 + (col - 256)] = f2bf(v);
        } else if (hroot) {
          hroot[(size_t)row * NPER * 256 + col] = f2bf(ftanh(v));
        } else if (uproj) {
          uproj[(size_t)row * 256 + col] = v;
        } else {
          ppdst[(size_t)(ppoff + row) * 256 + col] = f2bf(v);
        }
      }
    }
  }
}

// ---------------- LSTM elementwise ------------------------------------------

// s=0 sibling state for ALL depths (h_prev=c_prev=0, no gates).
__global__ __launch_bounds__(256) void k_lstm_s0(
    const u16* __restrict__ wihT, const float* __restrict__ bias,
    const int* __restrict__ feat, u16* __restrict__ h, u16* __restrict__ c) {
  int r = blockIdx.x, u = threadIdx.x;
  int off, pcs, start; ladder(r, off, pcs, start);
  int lg = r - off;
  int t = lg >> pcs, j = lg & ((1 << pcs) - 1);
  int idx = t * NPER + start + 4 * j;
  int lab = feat[idx];
  const u16* wr = wihT + lab * 1024;
  float gi = b2f(wr[u])       + bias[u];
  float gg = b2f(wr[512 + u]) + bias[512 + u];
  float go = b2f(wr[768 + u]) + bias[768 + u];
  float cn = fsigm(gi) * ftanh(gg);
  float hn = fsigm(go) * ftanh(cn);
  h[(size_t)r * 256 + u] = f2bf(hn);
  c[(size_t)r * 256 + u] = f2bf(cn);
}

// sibling step k (k=1,2), all depths batched; chain row r.
__global__ __launch_bounds__(256) void k_lstm_sibA(
    const u16* __restrict__ gates, const u16* __restrict__ wihT,
    const float* __restrict__ bias, const u16* __restrict__ c_in,
    const int* __restrict__ feat, u16* __restrict__ h, u16* __restrict__ c,
    int k) {
  int r = blockIdx.x, u = threadIdx.x;
  int off, pcs, start; ladder(r, off, pcs, start);
  int lg = r - off;
  int t = lg >> pcs, j = lg & ((1 << pcs) - 1);
  int idx = t * NPER + start + 4 * j + k;
  int lab = feat[idx];
  const u16* wr = wihT + lab * 1024;
  const u16* gr = gates + (size_t)r * 1024;
  float gi = b2f(wr[u])       + bias[u]       + b2f(gr[u]);
  float gf = b2f(wr[256 + u]) + bias[256 + u] + b2f(gr[256 + u]);
  float gg = b2f(wr[512 + u]) + bias[512 + u] + b2f(gr[512 + u]);
  float go = b2f(wr[768 + u]) + bias[768 + u] + b2f(gr[768 + u]);
  float cv = b2f(c_in[(size_t)r * 256 + u]);
  float cn = fsigm(gf) * cv + fsigm(gi) * ftanh(gg);
  float hn = fsigm(go) * ftanh(cn);
  h[(size_t)r * 256 + u] = f2bf(hn);
  c[(size_t)r * 256 + u] = f2bf(cn);
}

// parent LSTM, all 4 sibling groups of a depth at once.
__global__ __launch_bounds__(256) void k_lstm_par(
    const u16* __restrict__ gates, const u16* __restrict__ wihT,
    const float* __restrict__ bias, const u16* __restrict__ c_in,
    const int* __restrict__ feat, u16* __restrict__ h, u16* __restrict__ c,
    int lsbits, int start) {
  int g = blockIdx.x, u = threadIdx.x;
  int t = g >> lsbits, p = g & ((1 << lsbits) - 1);
  int pr = lsbits ? ((t << (lsbits - 2)) | (p >> 2)) : g;
  int idx = t * NPER + start + p;
  int lab = feat[idx];
  const u16* wr = wihT + lab * 1024;
  const u16* gr = gates + (size_t)pr * 1024;
  float gi = b2f(wr[u])       + bias[u]       + b2f(gr[u]);
  float gf = b2f(wr[256 + u]) + bias[256 + u] + b2f(gr[256 + u]);
  float gg = b2f(wr[512 + u]) + bias[512 + u] + b2f(gr[512 + u]);
  float go = b2f(wr[768 + u]) + bias[768 + u] + b2f(gr[768 + u]);
  float cv = c_in ? b2f(c_in[(size_t)pr * 256 + u]) : 0.f;
  float cn = fsigm(gf) * cv + fsigm(gi) * ftanh(gg);
  float hn = fsigm(go) * ftanh(cn);
  h[(size_t)g * 256 + u] = f2bf(hn);
  c[(size_t)g * 256 + u] = f2bf(cn);
}

// ---------------- hpred assembly: tanh(PP + UPROJ_s) for all d>=1 nodes -----
__global__ __launch_bounds__(256) void k_assemble(
    const u16* __restrict__ PPA, const float* __restrict__ U1,
    const float* __restrict__ U2, const float* __restrict__ U3,
    u16* __restrict__ HPRED) {
  int r = blockIdx.x, u = threadIdx.x;
  int off, pcs, start; ladder(r, off, pcs, start);
  int lg = r - off;
  int t = lg >> pcs, j = lg & ((1 << pcs) - 1);
  size_t base = ((size_t)(t * NPER + start + 4 * j)) * 256 + u;
  size_t ro = (size_t)r * 256 + u;
  float pp = b2f(PPA[ro]);
  HPRED[base]       = f2bf(ftanh(pp));
  HPRED[base + 256] = f2bf(ftanh(pp + U1[ro]));
  HPRED[base + 512] = f2bf(ftanh(pp + U2[ro]));
  HPRED[base + 768] = f2bf(ftanh(pp + U3[ro]));
}

// ---------------- fused tail: logits GEMM + log-softmax ---------------------
__global__ __launch_bounds__(256, 2) void k_mm_tail(
    const u16* __restrict__ A, const u16* __restrict__ B,
    const float* __restrict__ bias, float* __restrict__ out) {
  __shared__ __align__(16) u16 As[32 * 264];
  __shared__ float smax[32][4], ssum[32][4], slz[32];
  const int m0 = blockIdx.x * 32;
  const int tid = threadIdx.x;
  const int wave = tid >> 6, lane = tid & 63;
  const int quad = lane >> 4, lr = lane & 15;
  const int c0 = wave * 160;

#pragma unroll
  for (int c = 0; c < 4; ++c) {
    int idx = c * 256 + tid;
    int row = idx >> 5, ch = (idx & 31) << 3;
    *(bf16x8*)&As[row * 264 + ch] =
        *(const bf16x8*)(A + (size_t)(m0 + row) * 256 + ch);
  }
  __syncthreads();

  f32x4 acc[2][10] = {};
#pragma unroll
  for (int t = 0; t < 8; ++t) {
    bf16x8 af[2], bfr[10];
#pragma unroll
    for (int tm = 0; tm < 2; ++tm)
      af[tm] = *(const bf16x8*)&As[(tm * 16 + lr) * 264 + t * 32 + quad * 8];
#pragma unroll
    for (int tn = 0; tn < 10; ++tn)
      bfr[tn] = *(const bf16x8*)(B + (size_t)(c0 + tn * 16 + lr) * 256 +
                                 t * 32 + quad * 8);
#pragma unroll
    for (int tm = 0; tm < 2; ++tm)
#pragma unroll
      for (int tn = 0; tn < 10; ++tn)
        acc[tm][tn] = __builtin_amdgcn_mfma_f32_16x16x32_bf16(
            af[tm], bfr[tn], acc[tm][tn], 0, 0, 0);
  }

  float bv[10]; bool val[10];
#pragma unroll
  for (int tn = 0; tn < 10; ++tn) {
    int col = c0 + tn * 16 + lr;
    val[tn] = (col < VDIM);
    bv[tn] = (col < VD2) ? bias[col] : 0.f;
  }

#pragma unroll
  for (int tm = 0; tm < 2; ++tm) {
#pragma unroll
    for (int r = 0; r < 4; ++r) {
      float mx = -1e30f;
#pragma unroll
      for (int tn = 0; tn < 10; ++tn)
        if (val[tn]) mx = fmaxf(mx, acc[tm][tn][r] + bv[tn]);
#pragma unroll
      for (int o = 1; o < 16; o <<= 1) mx = fmaxf(mx, __shfl_xor(mx, o, 64));
      if (lr == 0) smax[tm * 16 + quad * 4 + r][wave] = mx;
    }
  }
  __syncthreads();
#pragma unroll
  for (int tm = 0; tm < 2; ++tm) {
#pragma unroll
    for (int r = 0; r < 4; ++r) {
      int row = tm * 16 + quad * 4 + r;
      float fm = fmaxf(fmaxf(smax[row][0], smax[row][1]),
                       fmaxf(smax[row][2], smax[row][3]));
      float se = 0.f;
#pragma unroll
      for (int tn = 0; tn < 10; ++tn)
        if (val[tn]) se += __expf(acc[tm][tn][r] + bv[tn] - fm);
#pragma unroll
      for (int o = 1; o < 16; o <<= 1) se += __shfl_xor(se, o, 64);
      if (lr == 0) ssum[row][wave] = se;
    }
  }
  __syncthreads();
  if (tid < 32) {
    float fm = fmaxf(fmaxf(smax[tid][0], smax[tid][1]),
                     fmaxf(smax[tid][2], smax[tid][3]));
    slz[tid] = fm + __logf(ssum[tid][0] + ssum[tid][1] +
                           ssum[tid][2] + ssum[tid][3]);
  }
  __syncthreads();

#pragma unroll
  for (int tm = 0; tm < 2; ++tm) {
#pragma unroll
    for (int tn = 0; tn < 10; ++tn) {
      int col = c0 + tn * 16 + lr;
      if (col >= VD2) continue;
#pragma unroll
      for (int r = 0; r < 4; ++r) {
        int row = tm * 16 + quad * 4 + r;
        float v = acc[tm][tn][r] + bv[tn];
        out[(size_t)(m0 + row) * VD2 + col] =
            (col < VDIM) ? (v - slz[row]) : fsigm(v);
      }
    }
  }
}

// ---------------- host ------------------------------------------------------

extern "C" void kernel_launch(void* const* d_in, const int* in_sizes, int n_in,
                              void* d_out, int out_size, void* d_ws, size_t ws_size,
                              hipStream_t stream) {
  const float* z    = (const float*)d_in[0];
  const int*   feat = (const int*)d_in[1];
  const float* Wihp = (const float*)d_in[2];
  const float* Whhp = (const float*)d_in[3];
  const float* bihp = (const float*)d_in[4];
  const float* bhhp = (const float*)d_in[5];
  const float* Wihs = (const float*)d_in[6];
  const float* Whhs = (const float*)d_in[7];
  const float* bihs = (const float*)d_in[8];
  const float* bhhs = (const float*)d_in[9];
  const float* Upar = (const float*)d_in[10];
  const float* Usib = (const float*)d_in[11];
  const float* Wlab = (const float*)d_in[12];
  const float* blab = (const float*)d_in[13];
  const float* Wd   = (const float*)d_in[14];
  const float* bd   = (const float*)d_in[15];
  const float* Ww   = (const float*)d_in[16];
  const float* bw   = (const float*)d_in[17];
  float* out = (float*)d_out;

  char* w = (char*)d_ws;
  auto alloc = [&](size_t bytes) {
    char* p = w; w += (bytes + 255) & ~(size_t)255; return p;
  };
  u16*   UPWHHP = (u16*)alloc((size_t)1280 * 256 * 2);
  u16*   USWHHS = (u16*)alloc((size_t)1280 * 256 * 2);
  u16*   ZBF    = (u16*)alloc((size_t)128 * 256 * 2);   // rows 64..127 pad
  u16*   WIHPT  = (u16*)alloc((size_t)VDIM * 1024 * 2);
  u16*   WIHST  = (u16*)alloc((size_t)VDIM * 1024 * 2);
  u16*   WEXT   = (u16*)alloc((size_t)640 * 256 * 2);   // rows 602..639 pad
  float* BE     = (float*)alloc(VD2 * 4);
  float* BP     = (float*)alloc(1024 * 4);
  float* BS     = (float*)alloc(1024 * 4);
  // sibling chain: 21824 chain rows (pad to 21888 = 171*128)
  const size_t CR = 21888;
  u16*   HSA[3], *CSA[3];
  for (int k = 0; k < 3; ++k) {
    HSA[k] = (u16*)alloc(CR * 256 * 2);
    CSA[k] = (u16*)alloc(CR * 256 * 2);
  }
  float* UPROJ[3];
  for (int k = 0; k < 3; ++k) UPROJ[k] = (float*)alloc(CR * 256 * 4);
  u16*   PPA   = (u16*)alloc(CR * 256 * 2);
  // parent chain ping-pong (max 16384 rows)
  const size_t SB = (size_t)16384 * 256 * 2;
  u16* HP[2] = {(u16*)alloc(SB), (u16*)alloc(SB)};
  u16* CP[2] = {(u16*)alloc(SB), (u16*)alloc(SB)};
  u16*   GATES  = (u16*)alloc(CR * 1024 * 2);           // sibling gates
  u16*   GATESP = (u16*)alloc((size_t)4096 * 1024 * 2); // parent gates
  u16*   HPRED  = (u16*)alloc((size_t)87424 * 256 * 2); // node-ordered, +pad

  const int ppoff[6] = {0, 0, 64, 320, 1344, 5440};     // PPA offset by depth

  // ---- pack + sibling s=0 states
  k_pack<<<8037, 256, 0, stream>>>(Upar, Whhp, Usib, Whhs, z, Wihp, Wihs,
                                   Wlab, Wd, Ww, blab, bd, bw, bihp, bhhp,
                                   bihs, bhhs, UPWHHP, USWHHS, ZBF, WIHPT,
                                   WIHST, WEXT, BE, BP, BS);
  k_lstm_s0<<<21824, 256, 0, stream>>>(WIHST, BS, feat, HSA[0], CSA[0]);

  // ---- sibling chain, batched across depths (21824 rows/step)
  // k=1: dual(HSA0) -> UPROJ1 + GATES ; LSTM -> HSA1
  k_dual<<<dim3(171, 10), 256, 0, stream>>>(HSA[0], USWHHS, nullptr, 0,
                                            UPROJ[0], nullptr, GATES, 21824);
  k_lstm_sibA<<<21824, 256, 0, stream>>>(GATES, WIHST, BS, CSA[0], feat,
                                         HSA[1], CSA[1], 1);
  // k=2
  k_dual<<<dim3(171, 10), 256, 0, stream>>>(HSA[1], USWHHS, nullptr, 0,
                                            UPROJ[1], nullptr, GATES, 21824);
  k_lstm_sibA<<<21824, 256, 0, stream>>>(GATES, WIHST, BS, CSA[1], feat,
                                         HSA[2], CSA[2], 2);
  // k=3: UPROJ only
  k_dual<<<dim3(171, 2), 256, 0, stream>>>(HSA[2], USWHHS, nullptr, 0,
                                           UPROJ[2], nullptr, nullptr, 21824);

  // ---- parent chain (depth-serial)
  // z-dual: root hpred -> HPRED, gates -> GATESP
  k_dual<<<dim3(1, 10), 256, 0, stream>>>(ZBF, UPWHHP, nullptr, 0, nullptr,
                                          HPRED, GATESP, 64);
  k_lstm_par<<<64, 256, 0, stream>>>(GATESP, WIHPT, BP, nullptr, feat,
                                     HP[0], CP[0], 0, 0);
  const int starts[6] = {0, 1, 5, 21, 85, 341};
  int cur = 0;
  for (int d = 0; d < 4; ++d) {
    // P_d -> PP(d+1) + gates for P_{d+1}
    const int M = 64 << (2 * d);
    k_dual<<<dim3((M + 127) / 128, 10), 256, 0, stream>>>(
        HP[cur], UPWHHP, PPA, ppoff[d + 1], nullptr, nullptr, GATESP, M);
    k_lstm_par<<<64 << (2 * (d + 1)), 256, 0, stream>>>(
        GATESP, WIHPT, BP, CP[cur], feat, HP[1 - cur], CP[1 - cur],
        2 * (d + 1), starts[d + 1]);
    cur = 1 - cur;
  }
  // P_4 -> PP(5) only
  k_dual<<<dim3(128, 2), 256, 0, stream>>>(HP[cur], UPWHHP, PPA, ppoff[5],
                                           nullptr, nullptr, nullptr, 16384);

  // ---- hpred assembly for all d>=1 nodes, then tail
  k_assemble<<<21824, 256, 0, stream>>>(PPA, UPROJ[0], UPROJ[1], UPROJ[2],
                                        HPRED);
  k_mm_tail<<<2730, 256, 0, stream>>>(HPRED, WEXT, BE, out);

  (void)in_sizes; (void)n_in; (void)out_size; (void)ws_size;
}